// Round 10
// baseline (1648.451 us; speedup 1.0000x reference)
//
#include <hip/hip_runtime.h>
#include <hip/hip_bf16.h>

typedef __attribute__((ext_vector_type(8))) short short8;
typedef __attribute__((ext_vector_type(4))) float f32x4;
typedef unsigned long long u64;
typedef unsigned int u32;

#define SQLEN 256
#define BATCH 128
#define HID   1024
#define G4    4096
#define NCLS  1000

static __device__ __forceinline__ float sigm(float x){ return 1.0f/(1.0f+__expf(-x)); }
static __device__ __forceinline__ float tanhx(float x){ return 2.0f/(1.0f+__expf(-2.0f*x)) - 1.0f; }
static __device__ __forceinline__ short bf16b(float x){
  __hip_bfloat16 h = __float2bfloat16(x);
  return __builtin_bit_cast(short, h);
}
static __device__ __forceinline__ float bf2f(short s){
  return __bfloat162float(__builtin_bit_cast(__hip_bfloat16, s));
}

// ---- prep: cast x [B][S][I] fp32 -> xbf [(s*128+b)][I] bf16 (permuted) ----
__global__ void cast_x_kernel(const float* __restrict__ x, short* __restrict__ xbf){
  int r = blockIdx.x;            // r = s*128 + b
  int s = r >> 7, b = r & 127;
  const float* src = x + ((size_t)b*SQLEN + s)*HID;
  short* dst = xbf + (size_t)r*HID;
  int k = threadIdx.x*4;
  float4 v = *(const float4*)(src + k);
  short4 o; o.x=bf16b(v.x); o.y=bf16b(v.y); o.z=bf16b(v.z); o.w=bf16b(v.w);
  *(short4*)(dst + k) = o;
}

__global__ void cast_w_kernel(const float* __restrict__ src, short* __restrict__ dst){
  int i = (blockIdx.x*256 + threadIdx.x)*4;
  float4 v = *(const float4*)(src + i);
  short4 o; o.x=bf16b(v.x); o.y=bf16b(v.y); o.z=bf16b(v.z); o.w=bf16b(v.w);
  *(short4*)(dst + i) = o;
}

__global__ void bias_kernel(const float* __restrict__ a, const float* __restrict__ b,
                            float* __restrict__ o){
  int i = blockIdx.x*256 + threadIdx.x;
  o[i] = a[i] + b[i];
}

// ---- phase 1: xw GEMM (M=32768,N=4096,K=1024), 256x256 tile, BK=64,
// 8 waves, 2-deep counted-vmcnt pipeline (T3+T4). The old 128x2-barrier
// structure measured ~491 TF here (ceiling ~830-900 per guide); the deep
// pipeline's lever is: NEVER drain vmcnt to 0 in the K-loop. Exactly 8
// global_load_lds per stage per wave -> s_waitcnt vmcnt(8) provably waits
// for K-tile kt+1 while kt+2's 8 loads stay in flight across both barriers.
// LDS is FRAGMENT-major (1KB per MFMA fragment, lane-contiguous 16B reads,
// conflict-free -- same pattern as the proven whh_s/As layouts), achieved
// under linear DMA by per-lane SOURCE address mapping (m173 pattern).
// LDS 128KB -> 1 block/CU; launch_bounds(512,2) caps VGPR at 256 (liveness
// ~190). XCD-chunked bijective swizzle kept (2048 = 8 x 256; bn fastest ->
// A-panels XCD-L2-resident; B is 8MB, L2/L3-resident).
// Output layout/epilogue identical to the proven version (lstm untouched).
__global__ __launch_bounds__(512,2) void gemm_xw_kernel(
    const short* __restrict__ A, const short* __restrict__ B,
    const float* __restrict__ bias, short* __restrict__ C)
{
  __shared__ __align__(16) short As[2][16384];   // 2 x 32 KB, frag-major
  __shared__ __align__(16) short Bs[2][16384];   // 2 x 32 KB, frag-major
  const int tid  = threadIdx.x;
  const int lane = tid & 63;
  const int wave = tid >> 6;          // 0..7
  const int l15  = lane & 15;
  const int quad = lane >> 4;
  const int swz = (((int)blockIdx.x & 7) << 8) + ((int)blockIdx.x >> 3);
  const int bm = swz >> 4;            // 0..127 (M-tile)
  const int bn = swz & 15;            // 0..15  (N-tile)
  const size_t r0 = (size_t)bm*256, n0 = (size_t)bn*256;
  const int wmr = wave >> 2;          // row-half   (0..1) -> 128 rows
  const int wnc = wave & 3;           // col-quarter(0..3) -> 64 cols

  f32x4 acc[8][4];
  #pragma unroll
  for (int m=0;m<8;++m)
    #pragma unroll
    for (int n=0;n<4;++n) acc[m][n] = (f32x4)0.0f;

  // stage K-tile kt into buffer buf: 8 gload_lds/thread. Round r, wave w
  // stages fragment f = r*8+w (A rounds 0..3, B rounds 4..7); LDS dst is
  // linear (base + r*8KB + wave*1KB + lane*16B == frag f's 1KB slot); the
  // GLOBAL src encodes the frag layout: row m*16+l15, k kit*32+quad*8.
  auto stage = [&](int buf, int kt){
    const int k0 = kt*64;
    #pragma unroll
    for (int r=0;r<4;++r){
      const int fa = r*8 + wave, m = fa>>1, kit = fa&1;
      __builtin_amdgcn_global_load_lds(
        (const void*)(A + (r0 + m*16 + l15)*HID + k0 + kit*32 + quad*8),
        (void*)((char*)&As[buf][0] + r*8192 + wave*1024), 16, 0, 0);
    }
    #pragma unroll
    for (int r=0;r<4;++r){
      const int fb = r*8 + wave, n = fb>>1, kit = fb&1;
      __builtin_amdgcn_global_load_lds(
        (const void*)(B + (n0 + n*16 + l15)*HID + k0 + kit*32 + quad*8),
        (void*)((char*)&Bs[buf][0] + r*8192 + wave*1024), 16, 0, 0);
    }
  };
  // compute one K-tile from buffer buf: 24 ds_read_b128 + 64 MFMA per wave
  auto compute = [&](int buf){
    #pragma unroll
    for (int kit=0;kit<2;++kit){
      short8 a[8], b[4];
      #pragma unroll
      for (int m=0;m<8;++m)
        a[m] = *(const short8*)((char*)&As[buf][0]
                                + ((wmr*8 + m)*2 + kit)*1024 + lane*16);
      #pragma unroll
      for (int n=0;n<4;++n)
        b[n] = *(const short8*)((char*)&Bs[buf][0]
                                + ((wnc*4 + n)*2 + kit)*1024 + lane*16);
      #pragma unroll
      for (int m=0;m<8;++m)
        #pragma unroll
        for (int n=0;n<4;++n)
          acc[m][n] = __builtin_amdgcn_mfma_f32_16x16x32_bf16(a[m], b[n], acc[m][n], 0,0,0);
    }
  };

  // prologue: 2 K-tiles in flight; wait only for the first (8 newest fly)
  stage(0, 0);
  stage(1, 1);
  asm volatile("s_waitcnt vmcnt(8)\n\ts_barrier" ::: "memory");

  for (int kt = 0; kt < 16; ++kt){
    compute(kt & 1);
    // all waves done READING buf[kt&1] before re-staging it
    asm volatile("s_waitcnt lgkmcnt(0)\n\ts_barrier" ::: "memory");
    if (kt + 2 < 16) stage(kt & 1, kt + 2);
    if (kt + 1 < 16){
      if (kt + 2 < 16)
        asm volatile("s_waitcnt vmcnt(8)\n\ts_barrier" ::: "memory");  // kt+1 landed, kt+2 in flight
      else
        asm volatile("s_waitcnt vmcnt(0)\n\ts_barrier" ::: "memory");  // tail
    }
  }

  // epilogue: identical pack/layout to the proven version.
  // wave-half = one s index: s_idx = bm*2 + wmr; batch row b = m*16+quad*4+rg.
  const int s_idx = bm*2 + wmr;
  #pragma unroll
  for (int n=0;n<4;++n){
    int s = (int)n0 + wnc*64 + n*16;      // gate-space col, multiple of 16
    float bs = bias[s + l15];
    int g = s >> 10, jgi = (s & 1023) >> 4;
    #pragma unroll
    for (int m=0;m<8;++m){
      #pragma unroll
      for (int rg=0; rg<4; ++rg){
        u32 w0 = (u32)(unsigned short)bf16b(acc[m][n][rg] + bs);
        u32 w1 = __shfl_down(w0, 1);
        u32 w2 = __shfl_down(w0, 2);
        u32 w3 = __shfl_down(w0, 3);
        if ((l15 & 3) == 0){
          u64 pk = (u64)w0 | ((u64)w1<<16) | ((u64)w2<<32) | ((u64)w3<<48);
          int b = m*16 + quad*4 + rg;     // batch b 0..127
          *(u64*)(C + (((size_t)s_idx*64 + jgi)*128 + b)*64 + g*16 + l15) = pk;
        }
      }
    }
  }
}

// ---- phase 2: persistent LSTM recurrence -- BYTE-EXACT R1 (962us).
// Every modification attempted (AGPR/VGPR pinning, per-wave release
// protocol, 3 fusion variants) regressed; this structure is banked. ----
__global__ __launch_bounds__(256,2) void lstm_kernel(
    const short* __restrict__ whh, const short* __restrict__ xw,
    short* __restrict__ h_all, u32* __restrict__ flags)
{
  __shared__ f32x4 part[2][4][4][64];   // [buf][wave][gate][lane] = 32 KB

  const int tid  = threadIdx.x;
  const int lane = tid & 63;
  const int wave = tid >> 6;            // K-slice 0..3 (256 each)
  const int l15  = lane & 15;
  const int quad = lane >> 4;
  const int bg = blockIdx.x & 7;        // batch group
  const int jg = blockIdx.x >> 3;       // 0..63
  const int b0 = bg*16;
  const int j0 = jg*16;
  const int ks0 = wave*256;

  __builtin_amdgcn_fence(__ATOMIC_ACQUIRE, "agent");  // once: clear stale L2

  // Whh slice, MFMA B-fragment layout (no pinning -- rounds 2/3)
  short8 Bf[4][8];
  #pragma unroll
  for (int g=0; g<4; ++g)
    #pragma unroll
    for (int kit=0; kit<8; ++kit)
      Bf[g][kit] = *(const short8*)(whh + (size_t)(g*1024 + j0 + l15)*HID
                                    + ks0 + kit*32 + quad*8);

  u32* fgrp = flags + bg*64;            // one flag per producer block

  // elementwise cell mapping: cell = tid (r 0..15 x jj 0..15)
  const int r  = tid >> 4;
  const int jj = tid & 15;
  const int ln = (r>>2)*16 + jj;        // frag lane of cell
  const int rg = r & 3;                 // frag reg of cell
  float cc = 0.0f;                      // cell state in register

  // prefetch xw for t=0
  short xwc[4];
  {
    const short* xb = xw + (((size_t)0*64 + jg)*128 + b0 + r)*64 + jj;
    #pragma unroll
    for (int g=0; g<4; ++g) xwc[g] = xb[g*16];
  }

  for (int t = 0; t < SQLEN; ++t){
    const short* hin  = h_all + (size_t)t*131072;
    short*       hout = h_all + (size_t)(t+1)*131072;

    // prefetch next step's xw early (independent of h)
    short xwn[4];
    if (t < SQLEN-1){
      const short* xb = xw + (((size_t)(t+1)*64 + jg)*128 + b0 + r)*64 + jj;
      #pragma unroll
      for (int g=0; g<4; ++g) xwn[g] = xb[g*16];
    }

    // per-wave spin: only the 16 producer blocks of THIS wave's K-slice.
    if (t){
      u32* fp = fgrp + wave*16 + l15;
      while (__hip_atomic_load(fp, __ATOMIC_RELAXED,
                               __HIP_MEMORY_SCOPE_AGENT) < (u32)t)
        __builtin_amdgcn_s_sleep(1);
      asm volatile("" ::: "memory");    // no hoist of h loads above the spin
    }

    // h fragments: plain cached coalesced 16B loads (fresh addresses)
    short8 Af[8];
    #pragma unroll
    for (int kit=0; kit<8; ++kit)
      Af[kit] = *(const short8*)(hin + (size_t)(b0 + l15)*HID
                                 + ks0 + kit*32 + quad*8);

    f32x4 acc[4];
    #pragma unroll
    for (int g=0; g<4; ++g) acc[g] = (f32x4)0.0f;
    #pragma unroll
    for (int kit=0; kit<8; ++kit)
      #pragma unroll
      for (int g=0; g<4; ++g)
        acc[g] = __builtin_amdgcn_mfma_f32_16x16x32_bf16(Af[kit], Bf[g][kit], acc[g],0,0,0);

    // single-pass cross-wave reduce, all 4 gates, double-buffered
    const int pb = t & 1;
    #pragma unroll
    for (int g=0; g<4; ++g) part[pb][wave][g][lane] = acc[g];
    __syncthreads();

    float gv[4];
    #pragma unroll
    for (int g=0; g<4; ++g){
      float s = bf2f(xwc[g]);
      #pragma unroll
      for (int w=0; w<4; ++w)
        s += ((const float*)&part[pb][w][g][ln])[rg];
      gv[g] = s;
    }

    float it = sigm(gv[0]), ft = sigm(gv[1]), ch = tanhx(gv[2]), ot = sigm(gv[3]);
    cc = cc*ft + it*ch;
    float hv = ot * tanhx(cc);

    // pack 4 adjacent cells -> one 8B write-through store
    u32 w0 = (u32)(unsigned short)bf16b(hv);
    u32 w1 = __shfl_down(w0, 1);
    u32 w2 = __shfl_down(w0, 2);
    u32 w3 = __shfl_down(w0, 3);
    if (!(tid & 3)){
      u64 hp = (u64)w0 | ((u64)w1<<16) | ((u64)w2<<32) | ((u64)w3<<48);
      __hip_atomic_store((u64*)(hout + (size_t)(b0 + r)*HID + j0 + jj), hp,
                         __ATOMIC_RELAXED, __HIP_MEMORY_SCOPE_AGENT);
    }
    xwc[0]=xwn[0]; xwc[1]=xwn[1]; xwc[2]=xwn[2]; xwc[3]=xwn[3];
    __syncthreads();   // all waves' h stores drained (vmcnt0 at barrier)

    if (t < SQLEN-1 && tid == 0)
      __hip_atomic_store(fgrp + jg, (u32)(t+1), __ATOMIC_RELAXED,
                         __HIP_MEMORY_SCOPE_AGENT);   // plain store, no RMW
  }
}

// ---- phase 3: out[b][c] = h[b]. Wfc[c] + bfc[c], fp32. 256 blocks:
// 32 b-groups x 8 class-slices of 125 (proven). ----
__global__ __launch_bounds__(256) void fc_kernel(const short* __restrict__ h,
    const float* __restrict__ wfc, const float* __restrict__ bfc, float* __restrict__ out)
{
  __shared__ float hs[4][1024];
  int tid = threadIdx.x;
  int b0 = (blockIdx.x >> 3)*4;
  int cs = (blockIdx.x & 7)*125;
  for (int i = tid; i < 4096; i += 256){
    int bb = i >> 10, k = i & 1023;
    hs[bb][k] = bf2f(h[(size_t)(b0+bb)*HID + k]);
  }
  __syncthreads();
  for (int c = cs + tid; c < cs + 125; c += 256){
    const float* w = wfc + (size_t)c*HID;
    float a0=0.f,a1=0.f,a2=0.f,a3=0.f;
    for (int k=0; k<1024; k+=4){
      float4 wv = *(const float4*)(w + k);
      a0 += wv.x*hs[0][k] + wv.y*hs[0][k+1] + wv.z*hs[0][k+2] + wv.w*hs[0][k+3];
      a1 += wv.x*hs[1][k] + wv.y*hs[1][k+1] + wv.z*hs[1][k+2] + wv.w*hs[1][k+3];
      a2 += wv.x*hs[2][k] + wv.y*hs[2][k+1] + wv.z*hs[2][k+2] + wv.w*hs[2][k+3];
      a3 += wv.x*hs[3][k] + wv.y*hs[3][k+1] + wv.z*hs[3][k+2] + wv.w*hs[3][k+3];
    }
    float bb = bfc[c];
    out[(size_t)(b0+0)*NCLS + c] = a0 + bb;
    out[(size_t)(b0+1)*NCLS + c] = a1 + bb;
    out[(size_t)(b0+2)*NCLS + c] = a2 + bb;
    out[(size_t)(b0+3)*NCLS + c] = a3 + bb;
  }
}

extern "C" void kernel_launch(void* const* d_in, const int* in_sizes, int n_in,
                              void* d_out, int out_size, void* d_ws, size_t ws_size,
                              hipStream_t stream) {
  const float* x   = (const float*)d_in[0];
  const float* Wxh = (const float*)d_in[1];
  const float* bxh = (const float*)d_in[2];
  const float* Whh = (const float*)d_in[3];
  const float* bhh = (const float*)d_in[4];
  const float* Wfc = (const float*)d_in[5];
  const float* bfc = (const float*)d_in[6];
  float* out = (float*)d_out;

  char* ws = (char*)d_ws;
  // h_all (257 x 256KB = 64.25MB) ALIASES xbf (64MB): xbf dead after gemm.
  short*    h_all = (short*)(ws + 0);
  short*    xbf   = (short*)(ws + 0);
  short*    wxhb  = (short*)(ws + 68157440);     // 65 MB
  short*    whhb  = (short*)(ws + 76546048);     // 73 MB
  float*    biasg = (float*)(ws + 84934656);     // 81 MB
  short*    xw    = (short*)(ws + 85983232);     // 82 MB, 256 MB gate-blocked
  u32*      flags = (u32*)(ws + 354418688);      // 512 producer flags

  hipMemsetAsync(flags, 0, 4096, stream);

  cast_x_kernel<<<32768, 256, 0, stream>>>(x, xbf);
  cast_w_kernel<<<4096, 256, 0, stream>>>(Wxh, wxhb);
  cast_w_kernel<<<4096, 256, 0, stream>>>(Whh, whhb);
  bias_kernel  <<<16,   256, 0, stream>>>(bxh, bhh, biasg);
  gemm_xw_kernel<<<2048, 512, 0, stream>>>(xbf, wxhb, biasg, xw);
  // xbf now dead; zero h_all[0] (t=0 input state)
  hipMemsetAsync(ws, 0, 262144, stream);
  lstm_kernel  <<<512,  256, 0, stream>>>(whhb, xw, h_all, flags);
  fc_kernel    <<<256,  256, 0, stream>>>(h_all + (size_t)SQLEN*131072, Wfc, bfc, out);
}

// Round 11
// 1602.886 us; speedup vs baseline: 1.0284x; 1.0284x over previous
//
#include <hip/hip_runtime.h>
#include <hip/hip_bf16.h>

typedef __attribute__((ext_vector_type(8))) short short8;
typedef __attribute__((ext_vector_type(4))) float f32x4;
typedef unsigned long long u64;
typedef unsigned int u32;

#define SQLEN 256
#define BATCH 128
#define HID   1024
#define G4    4096
#define NCLS  1000

static __device__ __forceinline__ float sigm(float x){ return 1.0f/(1.0f+__expf(-x)); }
static __device__ __forceinline__ float tanhx(float x){ return 2.0f/(1.0f+__expf(-2.0f*x)) - 1.0f; }
static __device__ __forceinline__ short bf16b(float x){
  __hip_bfloat16 h = __float2bfloat16(x);
  return __builtin_bit_cast(short, h);
}
static __device__ __forceinline__ float bf2f(short s){
  return __bfloat162float(__builtin_bit_cast(__hip_bfloat16, s));
}

// ---- prep: cast x [B][S][I] fp32 -> xbf [(s*128+b)][I] bf16 (permuted) ----
__global__ void cast_x_kernel(const float* __restrict__ x, short* __restrict__ xbf){
  int r = blockIdx.x;            // r = s*128 + b
  int s = r >> 7, b = r & 127;
  const float* src = x + ((size_t)b*SQLEN + s)*HID;
  short* dst = xbf + (size_t)r*HID;
  int k = threadIdx.x*4;
  float4 v = *(const float4*)(src + k);
  short4 o; o.x=bf16b(v.x); o.y=bf16b(v.y); o.z=bf16b(v.z); o.w=bf16b(v.w);
  *(short4*)(dst + k) = o;
}

__global__ void cast_w_kernel(const float* __restrict__ src, short* __restrict__ dst){
  int i = (blockIdx.x*256 + threadIdx.x)*4;
  float4 v = *(const float4*)(src + i);
  short4 o; o.x=bf16b(v.x); o.y=bf16b(v.y); o.z=bf16b(v.z); o.w=bf16b(v.w);
  *(short4*)(dst + i) = o;
}

__global__ void bias_kernel(const float* __restrict__ a, const float* __restrict__ b,
                            float* __restrict__ o){
  int i = blockIdx.x*256 + threadIdx.x;
  o[i] = a[i] + b[i];
}

// ---- phase 1: xw GEMM, 256x256 tile, BK=64, 8 waves, TRUE 8-phase
// schedule (T3+T4+T5). R10's coarse vmcnt(8) 2-deep pipeline was null
// (guide m196: coarse split without per-phase interleave HURTS). This is
// the faithful template port: 4 phases per K-tile, each
// {ds_read 4-8 x b128 | issue 2 gload_lds | barrier | lgkm-wait(compiler) |
//  setprio1 16xMFMA setprio0 | barrier}; counted vmcnt folded before the
// phase-closing barrier, NEVER 0 mid-loop.
// Issue schedule per thread (groups of 2 loads), target tile j:
//   A1(j)@(j-1)ph0  B0(j)@(j-2)ph1  A0(j)@(j-2)ph2  B1(j)@(j-2)ph3
// Slot-overwrite safety: each group's slots were last READ in the phase
// before its issue point (B-kit0 read ph0 -> staged ph1; A-kit0 read ph1 ->
// ph2; B-kit1 read ph2 -> ph3; A-kit1 read ph3 -> next-tile ph0).
// Counted waits (derived by enumerating outstanding groups):
//   W1 @ ph1-end guards kit1(kt):  newer groups = 5 -> vmcnt(10); kt=14: 8; kt=15: 0
//   W2 @ ph3-end guards kit0(kt+1): newer = 5 -> vmcnt(10); kt=14: 4; kt=15: skip
// LDS frag-major (1KB/fragment, lane*16B reads = 2-way conflict-free, so
// T2 swizzle unnecessary). Epilogue/addressing byte-identical to R10
// (passed). XCD swizzle kept. LDS 128KB -> 1 block/CU.
__global__ __launch_bounds__(512,2) void gemm_xw_kernel(
    const short* __restrict__ A, const short* __restrict__ B,
    const float* __restrict__ bias, short* __restrict__ C)
{
  __shared__ __align__(16) short As[2][16384];   // 2 x 32 KB, frag-major
  __shared__ __align__(16) short Bs[2][16384];
  const int tid  = threadIdx.x;
  const int lane = tid & 63;
  const int wave = tid >> 6;          // 0..7
  const int l15  = lane & 15;
  const int quad = lane >> 4;
  const int swz = (((int)blockIdx.x & 7) << 8) + ((int)blockIdx.x >> 3);
  const int bm = swz >> 4;            // 0..127 (M-tile)
  const int bn = swz & 15;            // 0..15  (N-tile)
  const size_t r0 = (size_t)bm*256, n0 = (size_t)bn*256;
  const int wmr = wave >> 2;          // row-half    -> 128 rows
  const int wnc = wave & 3;           // col-quarter -> 64 cols

  f32x4 acc[8][4];
  #pragma unroll
  for (int m=0;m<8;++m)
    #pragma unroll
    for (int n=0;n<4;++n) acc[m][n] = (f32x4)0.0f;

  // stage group: 2 gload_lds. A slot(m,kit) = (m*2+kit)*1KB; wave w owns
  // rows m = 2w, 2w+1 (union over 8 waves = all 16 frags per kit).
  auto stageA = [&](int buf, int j, int kit){
    const int k0 = j*64 + kit*32;
    #pragma unroll
    for (int i=0;i<2;++i){
      const int m = wave*2 + i;
      __builtin_amdgcn_global_load_lds(
        (const void*)(A + (r0 + m*16 + l15)*HID + k0 + quad*8),
        (void*)((char*)&As[buf][0] + (m*2+kit)*1024), 16, 0, 0);
    }
  };
  auto stageB = [&](int buf, int j, int kit){
    const int k0 = j*64 + kit*32;
    #pragma unroll
    for (int i=0;i<2;++i){
      const int n = wave*2 + i;
      __builtin_amdgcn_global_load_lds(
        (const void*)(B + (n0 + n*16 + l15)*HID + k0 + quad*8),
        (void*)((char*)&Bs[buf][0] + (n*2+kit)*1024), 16, 0, 0);
    }
  };

  #define BAR  asm volatile("s_barrier" ::: "memory")

  // prologue: steady-state issue order so kt=0 needs no special case:
  // B0(0) A0(0) B1(0) A1(0) B0(1) A0(1) B1(1)  (7 groups)
  stageB(0,0,0); stageA(0,0,0); stageB(0,0,1); stageA(0,0,1);
  stageB(1,1,0); stageA(1,1,0); stageB(1,1,1);
  // guard kit0(t0): newer than A0(0) = 5 groups = 10
  asm volatile("s_waitcnt vmcnt(10)" ::: "memory");
  BAR;

  #pragma unroll 1
  for (int kt = 0; kt < 16; ++kt){
    const int buf = kt & 1;
    char* Ab = (char*)&As[buf][0];
    char* Bb = (char*)&Bs[buf][0];
    // ================= kit 0 =================
    {
      short8 a[4], b[4], a2[4];
      // ---- ph0: read kit0 mh0 (4a + 4b); issue A1(kt+1) -> other buf ----
      #pragma unroll
      for (int i=0;i<4;++i) a[i] = *(const short8*)(Ab + ((wmr*8+i)*2+0)*1024 + lane*16);
      #pragma unroll
      for (int j=0;j<4;++j) b[j] = *(const short8*)(Bb + ((wnc*4+j)*2+0)*1024 + lane*16);
      if (kt+1 < 16) stageA((kt+1)&1, kt+1, 1);
      BAR;
      __builtin_amdgcn_s_setprio(1);
      #pragma unroll
      for (int i=0;i<4;++i)
        #pragma unroll
        for (int j=0;j<4;++j)
          acc[i][j] = __builtin_amdgcn_mfma_f32_16x16x32_bf16(a[i], b[j], acc[i][j], 0,0,0);
      __builtin_amdgcn_s_setprio(0);
      BAR;
      // ---- ph1: read kit0 mh1 (4a, reuse b); issue B0(kt+2) -> this buf ----
      #pragma unroll
      for (int i=0;i<4;++i) a2[i] = *(const short8*)(Ab + ((wmr*8+4+i)*2+0)*1024 + lane*16);
      if (kt+2 < 16) stageB(buf, kt+2, 0);
      BAR;
      __builtin_amdgcn_s_setprio(1);
      #pragma unroll
      for (int i=0;i<4;++i)
        #pragma unroll
        for (int j=0;j<4;++j)
          acc[4+i][j] = __builtin_amdgcn_mfma_f32_16x16x32_bf16(a2[i], b[j], acc[4+i][j], 0,0,0);
      __builtin_amdgcn_s_setprio(0);
      // W1: guard kit1(kt) before ph2 reads
      if (kt <= 13)      asm volatile("s_waitcnt vmcnt(10)" ::: "memory");
      else if (kt == 14) asm volatile("s_waitcnt vmcnt(8)"  ::: "memory");
      else               asm volatile("s_waitcnt vmcnt(0)"  ::: "memory");
      BAR;
    }
    // ================= kit 1 =================
    {
      short8 a[4], b[4], a2[4];
      // ---- ph2: read kit1 mh0; issue A0(kt+2) ----
      #pragma unroll
      for (int i=0;i<4;++i) a[i] = *(const short8*)(Ab + ((wmr*8+i)*2+1)*1024 + lane*16);
      #pragma unroll
      for (int j=0;j<4;++j) b[j] = *(const short8*)(Bb + ((wnc*4+j)*2+1)*1024 + lane*16);
      if (kt+2 < 16) stageA(buf, kt+2, 0);
      BAR;
      __builtin_amdgcn_s_setprio(1);
      #pragma unroll
      for (int i=0;i<4;++i)
        #pragma unroll
        for (int j=0;j<4;++j)
          acc[i][j] = __builtin_amdgcn_mfma_f32_16x16x32_bf16(a[i], b[j], acc[i][j], 0,0,0);
      __builtin_amdgcn_s_setprio(0);
      BAR;
      // ---- ph3: read kit1 mh1; issue B1(kt+2) ----
      #pragma unroll
      for (int i=0;i<4;++i) a2[i] = *(const short8*)(Ab + ((wmr*8+4+i)*2+1)*1024 + lane*16);
      if (kt+2 < 16) stageB(buf, kt+2, 1);
      BAR;
      __builtin_amdgcn_s_setprio(1);
      #pragma unroll
      for (int i=0;i<4;++i)
        #pragma unroll
        for (int j=0;j<4;++j)
          acc[4+i][j] = __builtin_amdgcn_mfma_f32_16x16x32_bf16(a2[i], b[j], acc[4+i][j], 0,0,0);
      __builtin_amdgcn_s_setprio(0);
      // W2: guard kit0(kt+1) before next ph0 reads
      if (kt <= 13)      asm volatile("s_waitcnt vmcnt(10)" ::: "memory");
      else if (kt == 14) asm volatile("s_waitcnt vmcnt(4)"  ::: "memory");
      BAR;
    }
  }
  #undef BAR

  // epilogue: byte-identical to R10 (passed). wave-half = s index.
  const int s_idx = bm*2 + wmr;
  #pragma unroll
  for (int n=0;n<4;++n){
    int s = (int)n0 + wnc*64 + n*16;
    float bs = bias[s + l15];
    int g = s >> 10, jgi = (s & 1023) >> 4;
    #pragma unroll
    for (int m=0;m<8;++m){
      #pragma unroll
      for (int rg=0; rg<4; ++rg){
        u32 w0 = (u32)(unsigned short)bf16b(acc[m][n][rg] + bs);
        u32 w1 = __shfl_down(w0, 1);
        u32 w2 = __shfl_down(w0, 2);
        u32 w3 = __shfl_down(w0, 3);
        if ((l15 & 3) == 0){
          u64 pk = (u64)w0 | ((u64)w1<<16) | ((u64)w2<<32) | ((u64)w3<<48);
          int b = m*16 + quad*4 + rg;     // batch b 0..127
          *(u64*)(C + (((size_t)s_idx*64 + jgi)*128 + b)*64 + g*16 + l15) = pk;
        }
      }
    }
  }
}

// ---- phase 2: persistent LSTM recurrence -- BYTE-EXACT R1 (962us, banked).
__global__ __launch_bounds__(256,2) void lstm_kernel(
    const short* __restrict__ whh, const short* __restrict__ xw,
    short* __restrict__ h_all, u32* __restrict__ flags)
{
  __shared__ f32x4 part[2][4][4][64];   // [buf][wave][gate][lane] = 32 KB

  const int tid  = threadIdx.x;
  const int lane = tid & 63;
  const int wave = tid >> 6;            // K-slice 0..3 (256 each)
  const int l15  = lane & 15;
  const int quad = lane >> 4;
  const int bg = blockIdx.x & 7;        // batch group
  const int jg = blockIdx.x >> 3;       // 0..63
  const int b0 = bg*16;
  const int j0 = jg*16;
  const int ks0 = wave*256;

  __builtin_amdgcn_fence(__ATOMIC_ACQUIRE, "agent");  // once: clear stale L2

  // Whh slice, MFMA B-fragment layout (no pinning -- rounds 2/3)
  short8 Bf[4][8];
  #pragma unroll
  for (int g=0; g<4; ++g)
    #pragma unroll
    for (int kit=0; kit<8; ++kit)
      Bf[g][kit] = *(const short8*)(whh + (size_t)(g*1024 + j0 + l15)*HID
                                    + ks0 + kit*32 + quad*8);

  u32* fgrp = flags + bg*64;            // one flag per producer block

  // elementwise cell mapping: cell = tid (r 0..15 x jj 0..15)
  const int r  = tid >> 4;
  const int jj = tid & 15;
  const int ln = (r>>2)*16 + jj;        // frag lane of cell
  const int rg = r & 3;                 // frag reg of cell
  float cc = 0.0f;                      // cell state in register

  // prefetch xw for t=0
  short xwc[4];
  {
    const short* xb = xw + (((size_t)0*64 + jg)*128 + b0 + r)*64 + jj;
    #pragma unroll
    for (int g=0; g<4; ++g) xwc[g] = xb[g*16];
  }

  for (int t = 0; t < SQLEN; ++t){
    const short* hin  = h_all + (size_t)t*131072;
    short*       hout = h_all + (size_t)(t+1)*131072;

    // prefetch next step's xw early (independent of h)
    short xwn[4];
    if (t < SQLEN-1){
      const short* xb = xw + (((size_t)(t+1)*64 + jg)*128 + b0 + r)*64 + jj;
      #pragma unroll
      for (int g=0; g<4; ++g) xwn[g] = xb[g*16];
    }

    // per-wave spin: only the 16 producer blocks of THIS wave's K-slice.
    if (t){
      u32* fp = fgrp + wave*16 + l15;
      while (__hip_atomic_load(fp, __ATOMIC_RELAXED,
                               __HIP_MEMORY_SCOPE_AGENT) < (u32)t)
        __builtin_amdgcn_s_sleep(1);
      asm volatile("" ::: "memory");    // no hoist of h loads above the spin
    }

    // h fragments: plain cached coalesced 16B loads (fresh addresses)
    short8 Af[8];
    #pragma unroll
    for (int kit=0; kit<8; ++kit)
      Af[kit] = *(const short8*)(hin + (size_t)(b0 + l15)*HID
                                 + ks0 + kit*32 + quad*8);

    f32x4 acc[4];
    #pragma unroll
    for (int g=0; g<4; ++g) acc[g] = (f32x4)0.0f;
    #pragma unroll
    for (int kit=0; kit<8; ++kit)
      #pragma unroll
      for (int g=0; g<4; ++g)
        acc[g] = __builtin_amdgcn_mfma_f32_16x16x32_bf16(Af[kit], Bf[g][kit], acc[g],0,0,0);

    // single-pass cross-wave reduce, all 4 gates, double-buffered
    const int pb = t & 1;
    #pragma unroll
    for (int g=0; g<4; ++g) part[pb][wave][g][lane] = acc[g];
    __syncthreads();

    float gv[4];
    #pragma unroll
    for (int g=0; g<4; ++g){
      float s = bf2f(xwc[g]);
      #pragma unroll
      for (int w=0; w<4; ++w)
        s += ((const float*)&part[pb][w][g][ln])[rg];
      gv[g] = s;
    }

    float it = sigm(gv[0]), ft = sigm(gv[1]), ch = tanhx(gv[2]), ot = sigm(gv[3]);
    cc = cc*ft + it*ch;
    float hv = ot * tanhx(cc);

    // pack 4 adjacent cells -> one 8B write-through store
    u32 w0 = (u32)(unsigned short)bf16b(hv);
    u32 w1 = __shfl_down(w0, 1);
    u32 w2 = __shfl_down(w0, 2);
    u32 w3 = __shfl_down(w0, 3);
    if (!(tid & 3)){
      u64 hp = (u64)w0 | ((u64)w1<<16) | ((u64)w2<<32) | ((u64)w3<<48);
      __hip_atomic_store((u64*)(hout + (size_t)(b0 + r)*HID + j0 + jj), hp,
                         __ATOMIC_RELAXED, __HIP_MEMORY_SCOPE_AGENT);
    }
    xwc[0]=xwn[0]; xwc[1]=xwn[1]; xwc[2]=xwn[2]; xwc[3]=xwn[3];
    __syncthreads();   // all waves' h stores drained (vmcnt0 at barrier)

    if (t < SQLEN-1 && tid == 0)
      __hip_atomic_store(fgrp + jg, (u32)(t+1), __ATOMIC_RELAXED,
                         __HIP_MEMORY_SCOPE_AGENT);   // plain store, no RMW
  }
}

// ---- phase 3: out[b][c] = h[b]. Wfc[c] + bfc[c], fp32. 256 blocks. ----
__global__ __launch_bounds__(256) void fc_kernel(const short* __restrict__ h,
    const float* __restrict__ wfc, const float* __restrict__ bfc, float* __restrict__ out)
{
  __shared__ float hs[4][1024];
  int tid = threadIdx.x;
  int b0 = (blockIdx.x >> 3)*4;
  int cs = (blockIdx.x & 7)*125;
  for (int i = tid; i < 4096; i += 256){
    int bb = i >> 10, k = i & 1023;
    hs[bb][k] = bf2f(h[(size_t)(b0+bb)*HID + k]);
  }
  __syncthreads();
  for (int c = cs + tid; c < cs + 125; c += 256){
    const float* w = wfc + (size_t)c*HID;
    float a0=0.f,a1=0.f,a2=0.f,a3=0.f;
    for (int k=0; k<1024; k+=4){
      float4 wv = *(const float4*)(w + k);
      a0 += wv.x*hs[0][k] + wv.y*hs[0][k+1] + wv.z*hs[0][k+2] + wv.w*hs[0][k+3];
      a1 += wv.x*hs[1][k] + wv.y*hs[1][k+1] + wv.z*hs[1][k+2] + wv.w*hs[1][k+3];
      a2 += wv.x*hs[2][k] + wv.y*hs[2][k+1] + wv.z*hs[2][k+2] + wv.w*hs[2][k+3];
      a3 += wv.x*hs[3][k] + wv.y*hs[3][k+1] + wv.z*hs[3][k+2] + wv.w*hs[3][k+3];
    }
    float bb = bfc[c];
    out[(size_t)(b0+0)*NCLS + c] = a0 + bb;
    out[(size_t)(b0+1)*NCLS + c] = a1 + bb;
    out[(size_t)(b0+2)*NCLS + c] = a2 + bb;
    out[(size_t)(b0+3)*NCLS + c] = a3 + bb;
  }
}

extern "C" void kernel_launch(void* const* d_in, const int* in_sizes, int n_in,
                              void* d_out, int out_size, void* d_ws, size_t ws_size,
                              hipStream_t stream) {
  const float* x   = (const float*)d_in[0];
  const float* Wxh = (const float*)d_in[1];
  const float* bxh = (const float*)d_in[2];
  const float* Whh = (const float*)d_in[3];
  const float* bhh = (const float*)d_in[4];
  const float* Wfc = (const float*)d_in[5];
  const float* bfc = (const float*)d_in[6];
  float* out = (float*)d_out;

  char* ws = (char*)d_ws;
  // h_all (257 x 256KB = 64.25MB) ALIASES xbf (64MB): xbf dead after gemm.
  short*    h_all = (short*)(ws + 0);
  short*    xbf   = (short*)(ws + 0);
  short*    wxhb  = (short*)(ws + 68157440);     // 65 MB
  short*    whhb  = (short*)(ws + 76546048);     // 73 MB
  float*    biasg = (float*)(ws + 84934656);     // 81 MB
  short*    xw    = (short*)(ws + 85983232);     // 82 MB, 256 MB gate-blocked
  u32*      flags = (u32*)(ws + 354418688);      // 512 producer flags

  hipMemsetAsync(flags, 0, 4096, stream);

  cast_x_kernel<<<32768, 256, 0, stream>>>(x, xbf);
  cast_w_kernel<<<4096, 256, 0, stream>>>(Wxh, wxhb);
  cast_w_kernel<<<4096, 256, 0, stream>>>(Whh, whhb);
  bias_kernel  <<<16,   256, 0, stream>>>(bxh, bhh, biasg);
  gemm_xw_kernel<<<2048, 512, 0, stream>>>(xbf, wxhb, biasg, xw);
  // xbf now dead; zero h_all[0] (t=0 input state)
  hipMemsetAsync(ws, 0, 262144, stream);
  lstm_kernel  <<<512,  256, 0, stream>>>(whhb, xw, h_all, flags);
  fc_kernel    <<<256,  256, 0, stream>>>(h_all + (size_t)SQLEN*131072, Wfc, bfc, out);
}